// Round 1
// baseline (207.566 us; speedup 1.0000x reference)
//
#include <hip/hip_runtime.h>

constexpr int TB = 256;
constexpr int BANDS = 28;
constexpr int NN = 512;
constexpr int W = NN + BANDS - 1;        // 539
constexpr int NB = 8;
constexpr int NR = 512;
constexpr int ROWS = NB * NR;            // 4096
constexpr long long OUT_HALF = (long long)NB * NR * NN * BANDS;  // 58,720,256

__global__ void init_ws_kernel(int* ws) {
  if (threadIdx.x < 2) ws[threadIdx.x] = 0;
}

// Stage one (b,r) row into LDS and compute Yg1 = Yg / (1 + sliding_sum(mask_b^2)).
__device__ __forceinline__ void stage_row(const float* __restrict__ inputs,
                                          const float* __restrict__ mask,
                                          int row, int r, int tid,
                                          float* sY, float* sY1,
                                          float* sM0, float* sMB) {
  const float* Yg = inputs + (long long)row * W;   // inputs[b, r, :]
  const float* m0 = mask + (long long)r * NN;      // mask[0, r, :]
  const float* mb = mask + (long long)row * NN;    // mask[b, r, :]
  for (int k = tid; k < W; k += TB) sY[k] = Yg[k];
  for (int k = tid; k < NN; k += TB) { sM0[k] = m0[k]; sMB[k] = mb[k]; }
  __syncthreads();
  for (int j = tid; j < W; j += TB) {
    int klo = j - (BANDS - 1); if (klo < 0) klo = 0;
    int khi = j;               if (khi > NN - 1) khi = NN - 1;
    float s = 0.f;
    // descending k == ascending roll-shift i: matches reference sum order
    for (int k = khi; k >= klo; --k) { float v = sMB[k]; s += v * v; }
    sY1[j] = sY[j] * (1.0f / (s + 1.0f));
  }
  __syncthreads();
}

__global__ __launch_bounds__(TB) void max_kernel(const float* __restrict__ inputs,
                                                 const float* __restrict__ mask,
                                                 int* __restrict__ ws) {
  __shared__ float sY[W], sY1[W], sM0[NN], sMB[NN];
  const int row = blockIdx.x;
  const int r = row & (NR - 1);
  const int tid = threadIdx.x;
  stage_row(inputs, mask, row, r, tid, sY, sY1, sM0, sMB);

  float lmax = 0.f, lmax1 = 0.f;
  for (int j = tid; j < W; j += TB) {
    int klo = j - (BANDS - 1); if (klo < 0) klo = 0;
    int khi = j;               if (khi > NN - 1) khi = NN - 1;
    float wm = 0.f;
    for (int c = klo; c <= khi; ++c) wm = fmaxf(wm, sM0[c]);
    lmax  = fmaxf(lmax,  wm * sY[j]);
    lmax1 = fmaxf(lmax1, wm * sY1[j]);
  }
  // wave64 butterfly then cross-wave reduce
  for (int off = 32; off > 0; off >>= 1) {
    lmax  = fmaxf(lmax,  __shfl_down(lmax,  off));
    lmax1 = fmaxf(lmax1, __shfl_down(lmax1, off));
  }
  __shared__ float red[8];
  const int wid = tid >> 6;
  if ((tid & 63) == 0) { red[wid] = lmax; red[4 + wid] = lmax1; }
  __syncthreads();
  if (tid == 0) {
    float m  = fmaxf(fmaxf(red[0], red[1]), fmaxf(red[2], red[3]));
    float m1 = fmaxf(fmaxf(red[4], red[5]), fmaxf(red[6], red[7]));
    atomicMax(ws + 0, __float_as_int(m));   // all values >= 0: int order == float order
    atomicMax(ws + 1, __float_as_int(m1));
  }
}

__global__ __launch_bounds__(TB) void write_kernel(const float* __restrict__ inputs,
                                                   const float* __restrict__ mask,
                                                   const int* __restrict__ ws,
                                                   float* __restrict__ out) {
  __shared__ float sY[W], sY1[W], sM0[NN], sMB[NN];
  const int row = blockIdx.x;
  const int r = row & (NR - 1);
  const int tid = threadIdx.x;
  stage_row(inputs, mask, row, r, tid, sY, sY1, sM0, sMB);

  const float invX  = 1.0f / __int_as_float(ws[0]);
  const float invX1 = 1.0f / __int_as_float(ws[1]);

  float4* outX  = reinterpret_cast<float4*>(out) + (long long)row * (NN * BANDS / 4);
  float4* outX1 = reinterpret_cast<float4*>(out + OUT_HALF) + (long long)row * (NN * BANDS / 4);

  // 28 = 7*4 -> each aligned float4 lies inside one c; c = idx/7, i0 = 4*(idx%7)
  for (int idx = tid; idx < NN * BANDS / 4; idx += TB) {
    int c = idx / 7;
    int q = idx - c * 7;
    int j0 = c + q * 4;
    float m = sM0[c];
    float4 vx, vx1;
    vx.x  = (m * sY[j0 + 0]) * invX;
    vx.y  = (m * sY[j0 + 1]) * invX;
    vx.z  = (m * sY[j0 + 2]) * invX;
    vx.w  = (m * sY[j0 + 3]) * invX;
    vx1.x = (m * sY1[j0 + 0]) * invX1;
    vx1.y = (m * sY1[j0 + 1]) * invX1;
    vx1.z = (m * sY1[j0 + 2]) * invX1;
    vx1.w = (m * sY1[j0 + 3]) * invX1;
    outX[idx]  = vx;
    outX1[idx] = vx1;
  }
}

extern "C" void kernel_launch(void* const* d_in, const int* in_sizes, int n_in,
                              void* d_out, int out_size, void* d_ws, size_t ws_size,
                              hipStream_t stream) {
  const float* inputs = (const float*)d_in[0];
  const float* mask   = (const float*)d_in[1];
  int* ws = (int*)d_ws;
  float* out = (float*)d_out;

  hipLaunchKernelGGL(init_ws_kernel, dim3(1), dim3(64), 0, stream, ws);
  hipLaunchKernelGGL(max_kernel,   dim3(ROWS), dim3(TB), 0, stream, inputs, mask, ws);
  hipLaunchKernelGGL(write_kernel, dim3(ROWS), dim3(TB), 0, stream, inputs, mask, ws, out);
}

// Round 3
// 134.250 us; speedup vs baseline: 1.5461x; 1.5461x over previous
//
#include <hip/hip_runtime.h>

typedef float f32x4 __attribute__((ext_vector_type(4)));

constexpr int TB = 256;
constexpr int BANDS = 28;
constexpr int NN = 512;
constexpr int W = NN + BANDS - 1;        // 539
constexpr int NB = 8;
constexpr int NR = 512;
constexpr int ROWS = NB * NR;            // 4096
constexpr long long OUT_HALF = (long long)NB * NR * NN * BANDS;  // 58,720,256
constexpr int Y1_STRIDE = 540;           // cached Yg1 row stride (16B-aligned rows)
constexpr int CACHE_OFF = 8448;          // float offset of Yg1 cache in ws (16B aligned)

// ---------------- stage-1: per-row Yg1 + windowed maxima ----------------
// MODE 0: atomicMax into ws[0..1] (fallback). MODE 1: store per-row maxima.
// MODE 2: additionally cache Yg1 rows in ws for the write kernel.
template <int MODE>
__global__ __launch_bounds__(TB) void max_kernel(const float* __restrict__ inputs,
                                                 const float* __restrict__ mask,
                                                 float* __restrict__ wsf) {
  __shared__ __align__(16) float sY[W], sY1[W], sM0[NN], sMB[NN];
  const int row = blockIdx.x;
  const int r = row & (NR - 1);
  const int tid = threadIdx.x;

  const float* Yg = inputs + (long long)row * W;
  const float* m0 = mask + (long long)r * NN;
  const float* mb = mask + (long long)row * NN;
  for (int k = tid; k < W; k += TB) sY[k] = Yg[k];
  for (int k = tid; k < NN; k += TB) { sM0[k] = m0[k]; sMB[k] = mb[k]; }
  __syncthreads();

  float* y1row = wsf + CACHE_OFF + (long long)row * Y1_STRIDE;
  for (int j = tid; j < W; j += TB) {
    int klo = j - (BANDS - 1); if (klo < 0) klo = 0;
    int khi = j;               if (khi > NN - 1) khi = NN - 1;
    float s = 0.f;
    // descending k == ascending roll-shift i: matches reference sum order
    for (int k = khi; k >= klo; --k) { float v = sMB[k]; s += v * v; }
    float y1 = sY[j] * (1.0f / (s + 1.0f));
    sY1[j] = y1;
    if (MODE == 2) y1row[j] = y1;
  }
  __syncthreads();

  float lmax = 0.f, lmax1 = 0.f;
  for (int j = tid; j < W; j += TB) {
    int klo = j - (BANDS - 1); if (klo < 0) klo = 0;
    int khi = j;               if (khi > NN - 1) khi = NN - 1;
    float wm = 0.f;
    for (int c = klo; c <= khi; ++c) wm = fmaxf(wm, sM0[c]);
    lmax  = fmaxf(lmax,  wm * sY[j]);
    lmax1 = fmaxf(lmax1, wm * sY1[j]);
  }
  for (int off = 32; off > 0; off >>= 1) {
    lmax  = fmaxf(lmax,  __shfl_down(lmax,  off));
    lmax1 = fmaxf(lmax1, __shfl_down(lmax1, off));
  }
  __shared__ float red[8];
  const int wid = tid >> 6;
  if ((tid & 63) == 0) { red[wid] = lmax; red[4 + wid] = lmax1; }
  __syncthreads();
  if (tid == 0) {
    float m  = fmaxf(fmaxf(red[0], red[1]), fmaxf(red[2], red[3]));
    float m1 = fmaxf(fmaxf(red[4], red[5]), fmaxf(red[6], red[7]));
    if (MODE == 0) {
      atomicMax((int*)wsf + 0, __float_as_int(m));   // all values >= 0
      atomicMax((int*)wsf + 1, __float_as_int(m1));
    } else {
      wsf[2 + row] = m;
      wsf[2 + ROWS + row] = m1;
    }
  }
}

__global__ void init_ws_kernel(int* ws) {
  if (threadIdx.x < 2) ws[threadIdx.x] = 0;
}

// ---------------- stage-2: reduce 2x4096 partial maxima (no atomics) ----------------
__global__ __launch_bounds__(TB) void reduce_kernel(float* __restrict__ wsf) {
  const int tid = threadIdx.x;
  float m = 0.f, m1 = 0.f;
  for (int i = tid; i < ROWS; i += TB) {
    m  = fmaxf(m,  wsf[2 + i]);
    m1 = fmaxf(m1, wsf[2 + ROWS + i]);
  }
  for (int off = 32; off > 0; off >>= 1) {
    m  = fmaxf(m,  __shfl_down(m,  off));
    m1 = fmaxf(m1, __shfl_down(m1, off));
  }
  __shared__ float red[8];
  const int wid = tid >> 6;
  if ((tid & 63) == 0) { red[wid] = m; red[4 + wid] = m1; }
  __syncthreads();
  if (tid == 0) {
    wsf[0] = fmaxf(fmaxf(red[0], red[1]), fmaxf(red[2], red[3]));
    wsf[1] = fmaxf(fmaxf(red[4], red[5]), fmaxf(red[6], red[7]));
  }
}

// ---------------- stage-3: normalized band-stack writes ----------------
template <bool CACHED>
__global__ __launch_bounds__(TB) void write_kernel(const float* __restrict__ inputs,
                                                   const float* __restrict__ mask,
                                                   const float* __restrict__ wsf,
                                                   float* __restrict__ out) {
  __shared__ __align__(16) float sY[W], sY1[Y1_STRIDE], sM0[NN], sMB[NN];
  const int row = blockIdx.x;
  const int r = row & (NR - 1);
  const int tid = threadIdx.x;

  const float* Yg = inputs + (long long)row * W;
  const float* m0 = mask + (long long)r * NN;
  for (int k = tid; k < W; k += TB) sY[k] = Yg[k];
  for (int k = tid; k < NN; k += TB) sM0[k] = m0[k];

  if (CACHED) {
    const f32x4* y1r = reinterpret_cast<const f32x4*>(wsf + CACHE_OFF + (long long)row * Y1_STRIDE);
    f32x4* s1v = reinterpret_cast<f32x4*>(sY1);
    for (int k = tid; k < Y1_STRIDE / 4; k += TB) s1v[k] = y1r[k];
    __syncthreads();
  } else {
    const float* mb = mask + (long long)row * NN;
    for (int k = tid; k < NN; k += TB) sMB[k] = mb[k];
    __syncthreads();
    for (int j = tid; j < W; j += TB) {
      int klo = j - (BANDS - 1); if (klo < 0) klo = 0;
      int khi = j;               if (khi > NN - 1) khi = NN - 1;
      float s = 0.f;
      for (int k = khi; k >= klo; --k) { float v = sMB[k]; s += v * v; }
      sY1[j] = sY[j] * (1.0f / (s + 1.0f));
    }
    __syncthreads();
  }

  const float invX  = 1.0f / wsf[0];
  const float invX1 = 1.0f / wsf[1];

  f32x4* outX  = reinterpret_cast<f32x4*>(out) + (long long)row * (NN * BANDS / 4);
  f32x4* outX1 = reinterpret_cast<f32x4*>(out + OUT_HALF) + (long long)row * (NN * BANDS / 4);

  // 28 = 7*4 -> each aligned float4 lies inside one c; c = idx/7, i0 = 4*(idx%7)
  for (int idx = tid; idx < NN * BANDS / 4; idx += TB) {
    int c = idx / 7;
    int q = idx - c * 7;
    int j0 = c + q * 4;
    float m = sM0[c];
    f32x4 vx, vx1;
    vx.x  = (m * sY[j0 + 0]) * invX;
    vx.y  = (m * sY[j0 + 1]) * invX;
    vx.z  = (m * sY[j0 + 2]) * invX;
    vx.w  = (m * sY[j0 + 3]) * invX;
    vx1.x = (m * sY1[j0 + 0]) * invX1;
    vx1.y = (m * sY1[j0 + 1]) * invX1;
    vx1.z = (m * sY1[j0 + 2]) * invX1;
    vx1.w = (m * sY1[j0 + 3]) * invX1;
    __builtin_nontemporal_store(vx,  &outX[idx]);
    __builtin_nontemporal_store(vx1, &outX1[idx]);
  }
}

extern "C" void kernel_launch(void* const* d_in, const int* in_sizes, int n_in,
                              void* d_out, int out_size, void* d_ws, size_t ws_size,
                              hipStream_t stream) {
  const float* inputs = (const float*)d_in[0];
  const float* mask   = (const float*)d_in[1];
  float* wsf = (float*)d_ws;
  float* out = (float*)d_out;

  const size_t need_partial = (size_t)(2 + 2 * ROWS) * sizeof(float);                    // ~32.8 KB
  const size_t need_cache   = ((size_t)CACHE_OFF + (size_t)ROWS * Y1_STRIDE) * sizeof(float); // ~8.9 MB

  if (ws_size >= need_cache) {
    hipLaunchKernelGGL(max_kernel<2>,    dim3(ROWS), dim3(TB), 0, stream, inputs, mask, wsf);
    hipLaunchKernelGGL(reduce_kernel,    dim3(1),    dim3(TB), 0, stream, wsf);
    hipLaunchKernelGGL(write_kernel<true>, dim3(ROWS), dim3(TB), 0, stream, inputs, mask, wsf, out);
  } else if (ws_size >= need_partial) {
    hipLaunchKernelGGL(max_kernel<1>,    dim3(ROWS), dim3(TB), 0, stream, inputs, mask, wsf);
    hipLaunchKernelGGL(reduce_kernel,    dim3(1),    dim3(TB), 0, stream, wsf);
    hipLaunchKernelGGL(write_kernel<false>, dim3(ROWS), dim3(TB), 0, stream, inputs, mask, wsf, out);
  } else {
    hipLaunchKernelGGL(init_ws_kernel,   dim3(1),    dim3(64), 0, stream, (int*)d_ws);
    hipLaunchKernelGGL(max_kernel<0>,    dim3(ROWS), dim3(TB), 0, stream, inputs, mask, wsf);
    hipLaunchKernelGGL(write_kernel<false>, dim3(ROWS), dim3(TB), 0, stream, inputs, mask, wsf, out);
  }
}

// Round 4
// 128.732 us; speedup vs baseline: 1.6124x; 1.0429x over previous
//
#include <hip/hip_runtime.h>

typedef float f32x4 __attribute__((ext_vector_type(4)));

constexpr int TB = 256;
constexpr int BANDS = 28;
constexpr int NN = 512;
constexpr int W = NN + BANDS - 1;        // 539
constexpr int NB = 8;
constexpr int NR = 512;
constexpr int ROWS = NB * NR;            // 4096
constexpr long long OUT_HALF = (long long)NB * NR * NN * BANDS;  // 58,720,256
constexpr int Y1_STRIDE = 540;           // cached Yg1 row stride (16B-aligned rows)
constexpr int CACHE_OFF = 8448;          // float offset of Yg1 cache in ws (16B aligned)

// ---------------- stage-1: per-row Yg1 + windowed maxima ----------------
// MODE 0: atomicMax into ws[0..1] (fallback). MODE 1: store per-row maxima.
// MODE 2: additionally cache Yg1 rows in ws for the write kernel.
template <int MODE>
__global__ __launch_bounds__(TB) void max_kernel(const float* __restrict__ inputs,
                                                 const float* __restrict__ mask,
                                                 float* __restrict__ wsf) {
  __shared__ __align__(16) float sY[W], sY1[W], sM0[NN], sMB[NN];
  const int row = blockIdx.x;
  const int r = row & (NR - 1);
  const int tid = threadIdx.x;

  const float* Yg = inputs + (long long)row * W;
  const float* m0 = mask + (long long)r * NN;
  const float* mb = mask + (long long)row * NN;
  for (int k = tid; k < W; k += TB) sY[k] = Yg[k];
  for (int k = tid; k < NN; k += TB) { sM0[k] = m0[k]; sMB[k] = mb[k]; }
  __syncthreads();

  float* y1row = wsf + CACHE_OFF + (long long)row * Y1_STRIDE;
  for (int j = tid; j < W; j += TB) {
    int klo = j - (BANDS - 1); if (klo < 0) klo = 0;
    int khi = j;               if (khi > NN - 1) khi = NN - 1;
    float s = 0.f;
    // descending k == ascending roll-shift i: matches reference sum order
    for (int k = khi; k >= klo; --k) { float v = sMB[k]; s += v * v; }
    float y1 = sY[j] * (1.0f / (s + 1.0f));
    sY1[j] = y1;
    if (MODE == 2) y1row[j] = y1;
  }
  __syncthreads();

  float lmax = 0.f, lmax1 = 0.f;
  for (int j = tid; j < W; j += TB) {
    int klo = j - (BANDS - 1); if (klo < 0) klo = 0;
    int khi = j;               if (khi > NN - 1) khi = NN - 1;
    float wm = 0.f;
    for (int c = klo; c <= khi; ++c) wm = fmaxf(wm, sM0[c]);
    lmax  = fmaxf(lmax,  wm * sY[j]);
    lmax1 = fmaxf(lmax1, wm * sY1[j]);
  }
  for (int off = 32; off > 0; off >>= 1) {
    lmax  = fmaxf(lmax,  __shfl_down(lmax,  off));
    lmax1 = fmaxf(lmax1, __shfl_down(lmax1, off));
  }
  __shared__ float red[8];
  const int wid = tid >> 6;
  if ((tid & 63) == 0) { red[wid] = lmax; red[4 + wid] = lmax1; }
  __syncthreads();
  if (tid == 0) {
    float m  = fmaxf(fmaxf(red[0], red[1]), fmaxf(red[2], red[3]));
    float m1 = fmaxf(fmaxf(red[4], red[5]), fmaxf(red[6], red[7]));
    if (MODE == 0) {
      atomicMax((int*)wsf + 0, __float_as_int(m));   // all values >= 0
      atomicMax((int*)wsf + 1, __float_as_int(m1));
    } else {
      wsf[2 + row] = m;
      wsf[2 + ROWS + row] = m1;
    }
  }
}

__global__ void init_ws_kernel(int* ws) {
  if (threadIdx.x < 2) ws[threadIdx.x] = 0;
}

// ---------------- stage-2: fused reduce + normalized band-stack writes ----------------
// RMODE 0: read final maxima from ws[0..1] (atomic fallback path).
// RMODE 1: every block redundantly reduces the 2x4096 per-row partials (L2-resident).
template <int RMODE, bool CACHED>
__global__ __launch_bounds__(TB) void write_kernel(const float* __restrict__ inputs,
                                                   const float* __restrict__ mask,
                                                   const float* __restrict__ wsf,
                                                   float* __restrict__ out) {
  __shared__ __align__(16) float sY[W], sY1[Y1_STRIDE], sM0[NN], sMB[NN];
  __shared__ float red[8];
  const int row = blockIdx.x;
  const int r = row & (NR - 1);
  const int tid = threadIdx.x;

  // ---- issue staging loads first (latency overlaps the reduce phase) ----
  const float* Yg = inputs + (long long)row * W;
  const float* m0 = mask + (long long)r * NN;
  for (int k = tid; k < W; k += TB) sY[k] = Yg[k];
  for (int k = tid; k < NN; k += TB) sM0[k] = m0[k];
  if (CACHED) {
    const f32x4* y1r = reinterpret_cast<const f32x4*>(wsf + CACHE_OFF + (long long)row * Y1_STRIDE);
    f32x4* s1v = reinterpret_cast<f32x4*>(sY1);
    for (int k = tid; k < Y1_STRIDE / 4; k += TB) s1v[k] = y1r[k];
  } else {
    const float* mb = mask + (long long)row * NN;
    for (int k = tid; k < NN; k += TB) sMB[k] = mb[k];
  }

  // ---- global-max: either read precomputed, or reduce partials in-block ----
  float invX, invX1;
  if (RMODE == 0) {
    invX  = 1.0f / wsf[0];
    invX1 = 1.0f / wsf[1];
    __syncthreads();
  } else {
    float m = 0.f, m1 = 0.f;
    for (int i = tid; i < ROWS; i += TB) {
      m  = fmaxf(m,  wsf[2 + i]);
      m1 = fmaxf(m1, wsf[2 + ROWS + i]);
    }
    for (int off = 32; off > 0; off >>= 1) {
      m  = fmaxf(m,  __shfl_down(m,  off));
      m1 = fmaxf(m1, __shfl_down(m1, off));
    }
    const int wid = tid >> 6;
    if ((tid & 63) == 0) { red[wid] = m; red[4 + wid] = m1; }
    __syncthreads();   // red[] + staging LDS all visible
    // every thread computes the final max locally (no second barrier needed)
    invX  = 1.0f / fmaxf(fmaxf(red[0], red[1]), fmaxf(red[2], red[3]));
    invX1 = 1.0f / fmaxf(fmaxf(red[4], red[5]), fmaxf(red[6], red[7]));
  }

  if (!CACHED) {
    for (int j = tid; j < W; j += TB) {
      int klo = j - (BANDS - 1); if (klo < 0) klo = 0;
      int khi = j;               if (khi > NN - 1) khi = NN - 1;
      float s = 0.f;
      for (int k = khi; k >= klo; --k) { float v = sMB[k]; s += v * v; }
      sY1[j] = sY[j] * (1.0f / (s + 1.0f));
    }
    __syncthreads();
  }

  f32x4* outX  = reinterpret_cast<f32x4*>(out) + (long long)row * (NN * BANDS / 4);
  f32x4* outX1 = reinterpret_cast<f32x4*>(out + OUT_HALF) + (long long)row * (NN * BANDS / 4);

  // 28 = 7*4 -> each aligned float4 lies inside one c; c = idx/7, i0 = 4*(idx%7)
  for (int idx = tid; idx < NN * BANDS / 4; idx += TB) {
    int c = idx / 7;
    int q = idx - c * 7;
    int j0 = c + q * 4;
    float m = sM0[c];
    f32x4 vx, vx1;
    vx.x  = (m * sY[j0 + 0]) * invX;
    vx.y  = (m * sY[j0 + 1]) * invX;
    vx.z  = (m * sY[j0 + 2]) * invX;
    vx.w  = (m * sY[j0 + 3]) * invX;
    vx1.x = (m * sY1[j0 + 0]) * invX1;
    vx1.y = (m * sY1[j0 + 1]) * invX1;
    vx1.z = (m * sY1[j0 + 2]) * invX1;
    vx1.w = (m * sY1[j0 + 3]) * invX1;
    outX[idx]  = vx;   // plain stores: keep L2 write-combining (fill-kernel path)
    outX1[idx] = vx1;
  }
}

extern "C" void kernel_launch(void* const* d_in, const int* in_sizes, int n_in,
                              void* d_out, int out_size, void* d_ws, size_t ws_size,
                              hipStream_t stream) {
  const float* inputs = (const float*)d_in[0];
  const float* mask   = (const float*)d_in[1];
  float* wsf = (float*)d_ws;
  float* out = (float*)d_out;

  const size_t need_partial = (size_t)(2 + 2 * ROWS) * sizeof(float);                    // ~32.8 KB
  const size_t need_cache   = ((size_t)CACHE_OFF + (size_t)ROWS * Y1_STRIDE) * sizeof(float); // ~8.9 MB

  if (ws_size >= need_cache) {
    hipLaunchKernelGGL(max_kernel<2>, dim3(ROWS), dim3(TB), 0, stream, inputs, mask, wsf);
    hipLaunchKernelGGL((write_kernel<1, true>), dim3(ROWS), dim3(TB), 0, stream, inputs, mask, wsf, out);
  } else if (ws_size >= need_partial) {
    hipLaunchKernelGGL(max_kernel<1>, dim3(ROWS), dim3(TB), 0, stream, inputs, mask, wsf);
    hipLaunchKernelGGL((write_kernel<1, false>), dim3(ROWS), dim3(TB), 0, stream, inputs, mask, wsf, out);
  } else {
    hipLaunchKernelGGL(init_ws_kernel, dim3(1), dim3(64), 0, stream, (int*)d_ws);
    hipLaunchKernelGGL(max_kernel<0>, dim3(ROWS), dim3(TB), 0, stream, inputs, mask, wsf);
    hipLaunchKernelGGL((write_kernel<0, false>), dim3(ROWS), dim3(TB), 0, stream, inputs, mask, wsf, out);
  }
}